// Round 13
// baseline (271.352 us; speedup 1.0000x reference)
//
#include <hip/hip_runtime.h>
#include <math.h>

#define WNUM 1792
#define HID 128

#define INV3C 0.5773502691896258f
#define INV2C 0.7071067811865476f
#define A0C   0.17677669529663687f   /* 1/sqrt(32) */
#define A1C   0.14433756729740643f   /* 1/sqrt(48) */
#define MAXDEG 64

typedef short bf8 __attribute__((ext_vector_type(8)));
typedef _Float16 f16x8 __attribute__((ext_vector_type(8)));
typedef _Float16 f16x4 __attribute__((ext_vector_type(4)));
typedef float f32x4 __attribute__((ext_vector_type(4)));

__device__ inline unsigned short f2bf(float f) {
  union { float f; unsigned u; } v; v.f = f;
  unsigned r = v.u + 0x7FFFu + ((v.u >> 16) & 1u);   // RNE
  return (unsigned short)(r >> 16);
}
__device__ inline float bf2f(unsigned short h) {
  union { unsigned u; float f; } v; v.u = ((unsigned)h) << 16;
  return v.f;
}
__device__ inline float wscale(int t) {
  if (t < 32) return A0C;
  if (t < 64) return A0C * INV3C;
  if (t < 96) return A1C;
  return A1C * INV2C;
}

// ---- prep: weight staging + cnt zeroing (layouts unchanged) ----
__global__ __launch_bounds__(256) void prep_kernel(
    const float* __restrict__ We1, const float* __restrict__ We2,
    const float* __restrict__ be2,
    unsigned short* __restrict__ we1x, _Float16* __restrict__ we2h,
    float* __restrict__ be2p, int* __restrict__ cntp, int N)
{
  int i = blockIdx.x * 256 + threadIdx.x;
  if (i < 28672) {
    int t = i >> 8, c = (i >> 6) & 3, lane = i & 63;
    int quad = lane >> 4, l15 = lane & 15;
    int col = t * 16 + l15;
    float sc = wscale(t);
    f16x8 v;
    #pragma unroll
    for (int j = 0; j < 8; ++j) {
      int k = c * 32 + quad * 8 + j;
      v[j] = (_Float16)(We2[(size_t)k * WNUM + col] * sc);
    }
    *(f16x8*)(we2h + (size_t)t * 2048 + c * 512 + lane * 8) = v;
  } else if (i < 29184) {
    int q = i - 28672;
    int c1 = q >> 6, lane = q & 63;
    int quad = lane >> 4, l15 = lane & 15;
    int col = c1 * 16 + l15;
    bf8 hh, ll;
    #pragma unroll
    for (int j = 0; j < 8; ++j) {
      int k = quad * 8 + j;
      float v = We1[k * HID + col];
      unsigned short hi = f2bf(v);
      hh[j] = (short)hi;
      ll[j] = (short)f2bf(v - bf2f(hi));
    }
    *(bf8*)(we1x + c1 * 1024 + lane * 8) = hh;
    *(bf8*)(we1x + c1 * 1024 + 512 + lane * 8) = ll;
  } else if (i < 30976) {
    int q = i - 29184;
    int t = q >> 4, l16 = q & 15;
    be2p[(t >> 1) * 32 + l16 * 2 + (t & 1)] = be2[q] * wscale(t);
  } else if (i < 30976 + N) {
    cntp[i - 30976] = 0;
  }
}

__device__ inline void chains2(const f16x8* a0, const f16x8* a1,
    f16x8 b0, f16x8 b1, f16x8 b2, f16x8 b3,
    f16x8 b4, f16x8 b5, f16x8 b6, f16x8 b7,
    float2 bias, f32x4* wa, f32x4* wb)
{
  f32x4 ca0 = {bias.x, bias.x, bias.x, bias.x};
  f32x4 cb0 = {bias.y, bias.y, bias.y, bias.y};
  f32x4 ca1 = ca0, cb1 = cb0;
  ca0 = __builtin_amdgcn_mfma_f32_16x16x32_f16(a0[0], b0, ca0, 0, 0, 0);
  cb0 = __builtin_amdgcn_mfma_f32_16x16x32_f16(a0[0], b4, cb0, 0, 0, 0);
  ca1 = __builtin_amdgcn_mfma_f32_16x16x32_f16(a1[0], b0, ca1, 0, 0, 0);
  cb1 = __builtin_amdgcn_mfma_f32_16x16x32_f16(a1[0], b4, cb1, 0, 0, 0);
  ca0 = __builtin_amdgcn_mfma_f32_16x16x32_f16(a0[1], b1, ca0, 0, 0, 0);
  cb0 = __builtin_amdgcn_mfma_f32_16x16x32_f16(a0[1], b5, cb0, 0, 0, 0);
  ca1 = __builtin_amdgcn_mfma_f32_16x16x32_f16(a1[1], b1, ca1, 0, 0, 0);
  cb1 = __builtin_amdgcn_mfma_f32_16x16x32_f16(a1[1], b5, cb1, 0, 0, 0);
  ca0 = __builtin_amdgcn_mfma_f32_16x16x32_f16(a0[2], b2, ca0, 0, 0, 0);
  cb0 = __builtin_amdgcn_mfma_f32_16x16x32_f16(a0[2], b6, cb0, 0, 0, 0);
  ca1 = __builtin_amdgcn_mfma_f32_16x16x32_f16(a1[2], b2, ca1, 0, 0, 0);
  cb1 = __builtin_amdgcn_mfma_f32_16x16x32_f16(a1[2], b6, cb1, 0, 0, 0);
  ca0 = __builtin_amdgcn_mfma_f32_16x16x32_f16(a0[3], b3, ca0, 0, 0, 0);
  cb0 = __builtin_amdgcn_mfma_f32_16x16x32_f16(a0[3], b7, cb0, 0, 0, 0);
  ca1 = __builtin_amdgcn_mfma_f32_16x16x32_f16(a1[3], b3, ca1, 0, 0, 0);
  cb1 = __builtin_amdgcn_mfma_f32_16x16x32_f16(a1[3], b7, cb1, 0, 0, 0);
  wa[0] = ca0; wb[0] = cb0; wa[1] = ca1; wb[1] = cb1;
}

__device__ inline void pair_mm(const _Float16* bL, const float* bp, int p,
                               const f16x8 (&af)[2][4], f32x4* wa, f32x4* wb)
{
  f16x8 b0 = *(const f16x8*)(bL);
  f16x8 b1 = *(const f16x8*)(bL + 512);
  f16x8 b2 = *(const f16x8*)(bL + 1024);
  f16x8 b3 = *(const f16x8*)(bL + 1536);
  f16x8 b4 = *(const f16x8*)(bL + 2048);
  f16x8 b5 = *(const f16x8*)(bL + 2560);
  f16x8 b6 = *(const f16x8*)(bL + 3072);
  f16x8 b7 = *(const f16x8*)(bL + 3584);
  float2 bias2 = *(const float2*)(bp + p * 32);
  chains2(af[0], af[1], b0, b1, b2, b3, b4, b5, b6, b7, bias2, wa, wb);
}

// ---- fused edge kernel: 4 waves x 32 edges; 4-buffer LDS, stage-ahead 3,
//      raw s_barrier + fine-grained vmcnt (prefetch stays in flight) ----
template <bool MSG>
__global__ __launch_bounds__(256, 2) void edge_kernel(
    const float* __restrict__ ea, const float* __restrict__ xsrc,
    const float* __restrict__ sh, const int* __restrict__ dst,
    const float* __restrict__ be1,
    const unsigned short* __restrict__ we1x, const _Float16* __restrict__ we2h,
    const float* __restrict__ be2p,
    float* __restrict__ outp, int* __restrict__ eidx, int* __restrict__ cntp, int E)
{
  const int lane = threadIdx.x & 63;
  const int w    = threadIdx.x >> 6;
  const int quad = lane >> 4;
  const int l16  = lane & 15;
  const int eb   = (blockIdx.x * 4 + w) * 32;

  // h staging (pre-loop) overlays the B buffers (K-loop) — 34.8 KB region
  __shared__ union SMem {
    _Float16 h[4][32][136];
    _Float16 B[4][4096];
  } uS;
  __shared__ _Float16 fss_s[4][16][32];
  __shared__ _Float16 fvv_s[4][16][32];
  __shared__ _Float16 s1h_s[4][16][32];
  __shared__ _Float16 v1h_s[4][16][3][32];
  __shared__ float4 vq_s[4][32];

  #define STAGE_PAIR(p) { \
    const _Float16* gsrc_ = we2h + (size_t)(p) * 4096; \
    _Float16* ldst_ = &uS.B[(p) & 3][0]; \
    __builtin_amdgcn_global_load_lds( \
      (const __attribute__((address_space(1))) void*)(gsrc_ + (w * 2) * 512 + lane * 8), \
      (__attribute__((address_space(3))) void*)(ldst_ + (w * 2) * 512), 16, 0, 0); \
    __builtin_amdgcn_global_load_lds( \
      (const __attribute__((address_space(1))) void*)(gsrc_ + (w * 2 + 1) * 512 + lane * 8), \
      (__attribute__((address_space(3))) void*)(ldst_ + (w * 2 + 1) * 512), 16, 0, 0); \
  }

  // slot-fill / count early
  if (lane < 32) {
    int ge = eb + lane;
    if (ge < E) {
      int node = dst[ge];
      int pos = atomicAdd(cntp + node, 1);
      if (MSG) { if (pos < MAXDEG) eidx[node * MAXDEG + pos] = ge; }
    }
  }

  // ---- stage per-edge factors ----
  {
    int e2 = lane >> 1, mg = lane & 1;
    int ge = eb + e2;
    if (ge < E) {
      const float* xp = xsrc + (size_t)ge * 64;
      float4 sq0 = *(const float4*)(xp + mg * 8);
      float4 sq1 = *(const float4*)(xp + mg * 8 + 4);
      float s1a[8] = {sq0.x,sq0.y,sq0.z,sq0.w,sq1.x,sq1.y,sq1.z,sq1.w};
      const float* vp = xp + 16 + mg * 24;
      float la[24];
      #pragma unroll
      for (int qv = 0; qv < 6; ++qv) {
        float4 t = *(const float4*)(vp + qv * 4);
        la[qv*4+0] = t.x; la[qv*4+1] = t.y; la[qv*4+2] = t.z; la[qv*4+3] = t.w;
      }
      float4 shq = *(const float4*)(sh + (size_t)ge * 4);
      float s2 = shq.x, v2x = shq.y, v2y = shq.z, v2z = shq.w;
      #pragma unroll
      for (int mi = 0; mi < 8; ++mi) {
        int m = mg * 8 + mi;
        float v1x = la[mi*3], v1y = la[mi*3+1], v1z = la[mi*3+2];
        fss_s[w][m][e2] = (_Float16)(s1a[mi] * s2);
        fvv_s[w][m][e2] = (_Float16)(v1x*v2x + v1y*v2y + v1z*v2z);
        s1h_s[w][m][e2] = (_Float16)s1a[mi];
        v1h_s[w][m][0][e2] = (_Float16)v1x;
        v1h_s[w][m][1][e2] = (_Float16)v1y;
        v1h_s[w][m][2][e2] = (_Float16)v1z;
      }
      if (mg == 0) vq_s[w][e2] = make_float4(v2x, v2y, v2z, s2);
    } else {
      #pragma unroll
      for (int mi = 0; mi < 8; ++mi) {
        int m = mg * 8 + mi;
        fss_s[w][m][e2] = (_Float16)0.f;
        fvv_s[w][m][e2] = (_Float16)0.f;
        s1h_s[w][m][e2] = (_Float16)0.f;
        v1h_s[w][m][0][e2] = (_Float16)0.f;
        v1h_s[w][m][1][e2] = (_Float16)0.f;
        v1h_s[w][m][2][e2] = (_Float16)0.f;
      }
      if (mg == 0) vq_s[w][e2] = make_float4(0,0,0,0);
    }
  }

  // ---- layer 1 ----
  {
    bf8 ah[2], al[2];
    #pragma unroll
    for (int g = 0; g < 2; ++g) {
      int gea = eb + g * 16 + l16; if (gea > E - 1) gea = E - 1;
      const float* ep = ea + (size_t)gea * 32 + quad * 8;
      float4 p0 = *(const float4*)ep;
      float4 p1 = *(const float4*)(ep + 4);
      float pv[8] = {p0.x,p0.y,p0.z,p0.w,p1.x,p1.y,p1.z,p1.w};
      #pragma unroll
      for (int j = 0; j < 8; ++j) {
        unsigned short hi = f2bf(pv[j]);
        ah[g][j] = (short)hi;
        al[g][j] = (short)f2bf(pv[j] - bf2f(hi));
      }
    }
    const unsigned short* wb1 = we1x + lane * 8;
    #pragma unroll 2
    for (int c = 0; c < 8; ++c) {
      bf8 bh = *(const bf8*)(wb1 + c * 1024);
      bf8 bl = *(const bf8*)(wb1 + c * 1024 + 512);
      float bias = be1[c * 16 + l16];
      #pragma unroll
      for (int g = 0; g < 2; ++g) {
        f32x4 hc = {bias, bias, bias, bias};
        hc = __builtin_amdgcn_mfma_f32_16x16x32_bf16(al[g], bh, hc, 0, 0, 0);
        hc = __builtin_amdgcn_mfma_f32_16x16x32_bf16(ah[g], bl, hc, 0, 0, 0);
        hc = __builtin_amdgcn_mfma_f32_16x16x32_bf16(ah[g], bh, hc, 0, 0, 0);
        #pragma unroll
        for (int r = 0; r < 4; ++r)
          uS.h[w][g * 16 + quad * 4 + r][c * 16 + l16] = (_Float16)fmaxf(hc[r], 0.f);
      }
    }
  }
  __syncthreads();

  // ---- A fragments (must finish before B-staging overwrites the overlay) ----
  f16x8 af[2][4];
  #pragma unroll
  for (int g = 0; g < 2; ++g)
    #pragma unroll
    for (int ch = 0; ch < 4; ++ch)
      af[g][ch] = *(const f16x8*)&uS.h[w][g * 16 + l16][ch * 32 + quad * 8];

  float4 vq[2][4];
  #pragma unroll
  for (int g = 0; g < 2; ++g)
    #pragma unroll
    for (int r = 0; r < 4; ++r) vq[g][r] = vq_s[w][g * 16 + quad * 4 + r];
  __syncthreads();

  // prologue: stage pairs 0,1,2 (6 loads); wait until pair 0 landed (<=4 outstanding)
  STAGE_PAIR(0)
  STAGE_PAIR(1)
  STAGE_PAIR(2)
  __builtin_amdgcn_s_waitcnt(0xF74);
  __builtin_amdgcn_s_barrier();

  const float* bp = be2p + l16 * 2;
  float m0a[2][4] = {{0,0,0,0},{0,0,0,0}}, m0b[2][4] = {{0,0,0,0},{0,0,0,0}};
  float sg[2][4]  = {{0,0,0,0},{0,0,0,0}};
  float ux[2][4]  = {{0,0,0,0},{0,0,0,0}}, uy[2][4] = {{0,0,0,0},{0,0,0,0}},
        uz[2][4]  = {{0,0,0,0},{0,0,0,0}};
  float m1x[2][4], m1y[2][4], m1z[2][4];

  #pragma unroll 1
  for (int p = 0; p < 56; ++p) {
    if (p + 3 < 56) STAGE_PAIR(p + 3)

    f32x4 wa[2], wb[2];
    pair_mm(&uS.B[p & 3][lane * 8], bp, p, af, wa, wb);

    if (p < 16) {
      #pragma unroll
      for (int g = 0; g < 2; ++g) {
        f16x4 fv = *(const f16x4*)&fss_s[w][p][g * 16 + quad * 4];
        #pragma unroll
        for (int r = 0; r < 4; ++r) {
          float f = (float)fv[r];
          m0a[g][r] = fmaf(wa[g][r], f, m0a[g][r]);
          m0b[g][r] = fmaf(wb[g][r], f, m0b[g][r]);
        }
      }
    } else if (p < 32) {
      #pragma unroll
      for (int g = 0; g < 2; ++g) {
        f16x4 fv = *(const f16x4*)&fvv_s[w][p - 16][g * 16 + quad * 4];
        #pragma unroll
        for (int r = 0; r < 4; ++r) {
          float f = (float)fv[r];
          m0a[g][r] = fmaf(wa[g][r], f, m0a[g][r]);
          m0b[g][r] = fmaf(wb[g][r], f, m0b[g][r]);
        }
      }
    } else if (p < 40) {
      int j = 2 * (p - 32);
      #pragma unroll
      for (int g = 0; g < 2; ++g) {
        f16x4 sA = *(const f16x4*)&s1h_s[w][j][g * 16 + quad * 4];
        f16x4 sB = *(const f16x4*)&s1h_s[w][j + 1][g * 16 + quad * 4];
        #pragma unroll
        for (int r = 0; r < 4; ++r)
          sg[g][r] = fmaf(wb[g][r], (float)sB[r], fmaf(wa[g][r], (float)sA[r], sg[g][r]));
      }
    } else {
      int j = 2 * (p - (p < 48 ? 40 : 48));
      #pragma unroll
      for (int g = 0; g < 2; ++g) {
        f16x4 xA = *(const f16x4*)&v1h_s[w][j][0][g*16 + quad*4];
        f16x4 xB = *(const f16x4*)&v1h_s[w][j+1][0][g*16 + quad*4];
        f16x4 yA = *(const f16x4*)&v1h_s[w][j][1][g*16 + quad*4];
        f16x4 yB = *(const f16x4*)&v1h_s[w][j+1][1][g*16 + quad*4];
        f16x4 zA = *(const f16x4*)&v1h_s[w][j][2][g*16 + quad*4];
        f16x4 zB = *(const f16x4*)&v1h_s[w][j+1][2][g*16 + quad*4];
        #pragma unroll
        for (int r = 0; r < 4; ++r) {
          ux[g][r] = fmaf(wb[g][r], (float)xB[r], fmaf(wa[g][r], (float)xA[r], ux[g][r]));
          uy[g][r] = fmaf(wb[g][r], (float)yB[r], fmaf(wa[g][r], (float)yA[r], uy[g][r]));
          uz[g][r] = fmaf(wb[g][r], (float)zB[r], fmaf(wa[g][r], (float)zA[r], uz[g][r]));
        }
      }
    }

    // fine-grained fence: wait only until pair p+1's loads landed
    // (pairs p+2, p+3 remain in flight across the raw barrier)
    if (p < 53) __builtin_amdgcn_s_waitcnt(0xF72);
    else        __builtin_amdgcn_s_waitcnt(0xF70);
    __builtin_amdgcn_s_barrier();

    if (p == 31) {
      // emit out0 (sections 1+2 done)
      #pragma unroll
      for (int g = 0; g < 2; ++g)
        #pragma unroll
        for (int r = 0; r < 4; ++r) {
          int ge = eb + g * 16 + quad * 4 + r;
          if (ge < E) {
            if (MSG) {
              float* mp = outp + (size_t)ge * 80;
              mp[l16]      = m0a[g][r];
              mp[16 + l16] = m0b[g][r];
            } else {
              float* ap = outp + (size_t)dst[ge] * 80;
              atomicAdd(ap + l16,      m0a[g][r]);
              atomicAdd(ap + 16 + l16, m0b[g][r]);
            }
          }
        }
    } else if (p == 39) {
      #pragma unroll
      for (int g = 0; g < 2; ++g)
        #pragma unroll
        for (int r = 0; r < 4; ++r) {
          m1x[g][r] = sg[g][r] * vq[g][r].x;
          m1y[g][r] = sg[g][r] * vq[g][r].y;
          m1z[g][r] = sg[g][r] * vq[g][r].z;
        }
    } else if (p == 47) {
      #pragma unroll
      for (int g = 0; g < 2; ++g)
        #pragma unroll
        for (int r = 0; r < 4; ++r) {
          m1x[g][r] = fmaf(vq[g][r].w, ux[g][r], m1x[g][r]);
          m1y[g][r] = fmaf(vq[g][r].w, uy[g][r], m1y[g][r]);
          m1z[g][r] = fmaf(vq[g][r].w, uz[g][r], m1z[g][r]);
          ux[g][r] = 0.f; uy[g][r] = 0.f; uz[g][r] = 0.f;
        }
    }
  }

  // vv1 tail: m1 += cross(u, v2)
  #pragma unroll
  for (int g = 0; g < 2; ++g)
    #pragma unroll
    for (int r = 0; r < 4; ++r) {
      m1x[g][r] = fmaf(uy[g][r], vq[g][r].z, m1x[g][r]);
      m1x[g][r] = fmaf(-uz[g][r], vq[g][r].y, m1x[g][r]);
      m1y[g][r] = fmaf(uz[g][r], vq[g][r].x, m1y[g][r]);
      m1y[g][r] = fmaf(-ux[g][r], vq[g][r].z, m1y[g][r]);
      m1z[g][r] = fmaf(ux[g][r], vq[g][r].y, m1z[g][r]);
      m1z[g][r] = fmaf(-uy[g][r], vq[g][r].x, m1z[g][r]);
    }

  // ---- emit out1 ----
  #pragma unroll
  for (int g = 0; g < 2; ++g)
    #pragma unroll
    for (int r = 0; r < 4; ++r) {
      int ge = eb + g * 16 + quad * 4 + r;
      if (ge < E) {
        if (MSG) {
          float* mp = outp + (size_t)ge * 80;
          mp[32 + l16*3 + 0] = m1x[g][r];
          mp[32 + l16*3 + 1] = m1y[g][r];
          mp[32 + l16*3 + 2] = m1z[g][r];
        } else {
          float* ap = outp + (size_t)dst[ge] * 80;
          atomicAdd(ap + 32 + l16*3 + 0, m1x[g][r]);
          atomicAdd(ap + 32 + l16*3 + 1, m1y[g][r]);
          atomicAdd(ap + 32 + l16*3 + 2, m1z[g][r]);
        }
      }
    }
  #undef STAGE_PAIR
}

// ---- node gather (MSG path) ----
__global__ __launch_bounds__(128) void node_gather_kernel(
    const float* __restrict__ msg, const int* __restrict__ eidx,
    const int* __restrict__ cntp,
    const float* __restrict__ xdst, const float* __restrict__ Wr0,
    const float* __restrict__ Wr1, float* __restrict__ out, int N)
{
  int n = blockIdx.x;
  if (n >= N) return;
  int j = threadIdx.x;
  int c0 = cntp[n];
  int deg = c0 < MAXDEG ? c0 : MAXDEG;
  float inv = 1.0f / fmaxf((float)c0, 1.0f);
  __shared__ float s_sum[80];
  if (j < 80) {
    float s = 0.f;
    const int* ep = eidx + (size_t)n * MAXDEG;
    int i = 0;
    for (; i + 1 < deg; i += 2) {
      int e0 = ep[i], e1 = ep[i + 1];
      s += msg[(size_t)e0 * 80 + j] + msg[(size_t)e1 * 80 + j];
    }
    if (i < deg) s += msg[(size_t)ep[i] * 80 + j];
    s_sum[j] = s * inv;
  }
  __syncthreads();
  if (j >= 64) return;
  const float* xd = xdst + (size_t)n * 64;
  float* op = out + (size_t)n * 64;
  if (j < 16) {
    float s = 0.f;
    #pragma unroll
    for (int m = 0; m < 16; ++m) s = fmaf(xd[m], Wr0[m * 32 + j], s);
    op[j] = fmaxf(s_sum[j] + 0.25f * s, 0.f);
  } else {
    int jj = j - 16;
    int o = (jj * 86) >> 8;
    int c = jj - o * 3;
    float tg = 0.f, v = 0.f;
    #pragma unroll
    for (int m = 0; m < 16; ++m) {
      tg = fmaf(xd[m], Wr0[m * 32 + 16 + o], tg);
      v  = fmaf(xd[16 + m * 3 + c], Wr1[m * 16 + o], v);
    }
    float g = 1.0f / (1.0f + expf(-(s_sum[16 + o] + 0.25f * tg)));
    op[16 + jj] = (s_sum[32 + jj] + 0.25f * v) * g;
  }
}

// ---- node epilogue (atomic fallback path) ----
__global__ __launch_bounds__(256) void node_kernel(
    const float* __restrict__ accn, const int* __restrict__ cntp,
    const float* __restrict__ xdst, const float* __restrict__ Wr0,
    const float* __restrict__ Wr1, float* __restrict__ out, int N)
{
  int idx = blockIdx.x * 256 + threadIdx.x;
  int n = idx >> 6, j = idx & 63;
  if (n >= N) return;
  float inv = 1.0f / fmaxf((float)cntp[n], 1.0f);
  const float* ap = accn + (size_t)n * 80;
  const float* xd = xdst + (size_t)n * 64;
  float* op = out + (size_t)n * 64;
  if (j < 16) {
    float s = 0.f;
    #pragma unroll
    for (int m = 0; m < 16; ++m) s = fmaf(xd[m], Wr0[m * 32 + j], s);
    op[j] = fmaxf(ap[j] * inv + 0.25f * s, 0.f);
  } else {
    int jj = j - 16;
    int o = (jj * 86) >> 8;
    int c = jj - o * 3;
    float tg = 0.f, v = 0.f;
    #pragma unroll
    for (int m = 0; m < 16; ++m) {
      tg = fmaf(xd[m], Wr0[m * 32 + 16 + o], tg);
      v  = fmaf(xd[16 + m * 3 + c], Wr1[m * 16 + o], v);
    }
    float g = 1.0f / (1.0f + expf(-(ap[16 + o] * inv + 0.25f * tg)));
    op[16 + jj] = (ap[32 + jj] * inv + 0.25f * v) * g;
  }
}

extern "C" void kernel_launch(void* const* d_in, const int* in_sizes, int n_in,
                              void* d_out, int out_size, void* d_ws, size_t ws_size,
                              hipStream_t stream)
{
  const int*   dst  = (const int*)d_in[0];
  const float* xsrc = (const float*)d_in[1];
  const float* xdst = (const float*)d_in[2];
  const float* sh   = (const float*)d_in[3];
  const float* ea   = (const float*)d_in[4];
  const float* We1  = (const float*)d_in[5];
  const float* be1  = (const float*)d_in[6];
  const float* We2  = (const float*)d_in[7];
  const float* be2  = (const float*)d_in[8];
  const float* Wr0  = (const float*)d_in[9];
  const float* Wr1  = (const float*)d_in[10];
  const int E = in_sizes[0];
  const int N = in_sizes[2] / 64;

  char* ws = (char*)d_ws;
  _Float16* we2h = (_Float16*)ws;                           // 458,752 B
  unsigned short* we1x = (unsigned short*)(ws + 458752);    //  16,384 B
  float* be2p = (float*)(ws + 475136);                      //   7,424 B
  int*   cntp = (int*)(ws + 482560);                        // N*4
  size_t off = 482560 + (size_t)N * 4;
  off = (off + 15) & ~(size_t)15;

  size_t need_msg = off + (size_t)N * MAXDEG * 4 + (size_t)E * 80 * 4;
  bool use_msg = (ws_size >= need_msg);

  prep_kernel<<<(30976 + N + 255) / 256, 256, 0, stream>>>(We1, We2, be2,
      we1x, we2h, be2p, cntp, N);

  if (use_msg) {
    int* eidx = (int*)(ws + off);
    float* msg = (float*)(ws + off + (size_t)N * MAXDEG * 4);
    edge_kernel<true><<<(E + 127) / 128, 256, 0, stream>>>(ea, xsrc, sh, dst, be1,
        we1x, we2h, be2p, msg, eidx, cntp, E);
    node_gather_kernel<<<N, 128, 0, stream>>>(msg, eidx, cntp, xdst, Wr0, Wr1,
        (float*)d_out, N);
  } else {
    float* accn = (float*)(ws + off);
    hipMemsetAsync(accn, 0, (size_t)N * 320, stream);
    edge_kernel<false><<<(E + 127) / 128, 256, 0, stream>>>(ea, xsrc, sh, dst, be1,
        we1x, we2h, be2p, accn, (int*)nullptr, cntp, E);
    node_kernel<<<((size_t)N * 64 + 255) / 256, 256, 0, stream>>>(accn, cntp,
        xdst, Wr0, Wr1, (float*)d_out, N);
  }
}